// Round 2
// baseline (1474.396 us; speedup 1.0000x reference)
//
#include <hip/hip_runtime.h>
#include <hip/hip_bf16.h>

// GGNN fused scan. B=128 graphs, N=128 nodes, E=64, T=32, R=32.
// All float tensors are float32 (reference dtype). Internal LDS caches:
// H (f32, hidden @ W_in_top), hid (bf16 hidden state), relWb (bf16,
// b_in + rel_table @ W_in_bot).
//  - ggnn_pre (1024 blocks): NT[b,i,{r,z,t},e] = now_in @ W_m_top + b_m,
//    Hws[b,j,e] = node_emb @ W_in_top  -> d_ws (16.8 MB f32).
//  - ggnn_main (128 blocks = one per batch, 256 thr): sequential scan; GRU
//    bottom 64x64 weight columns in per-lane registers (wave0=Wr_bot,
//    wave1=Wz_bot, wave2=Wt_bot, wave3=W_in_top for the H row update).
//  - steps i >= input_length[b] are exact no-ops -> loop only to len.

#define B_ 128
#define N_ 128

typedef unsigned short u16;
typedef unsigned int u32;

__device__ __forceinline__ float b2f(u16 u) {
    union { u32 i; float f; } c; c.i = ((u32)u) << 16; return c.f;
}
__device__ __forceinline__ u16 f2b(float f) {
    union { float f; u32 i; } c; c.f = f;
    u32 u = c.i;
    u32 r = (u + 0x7fffu + ((u >> 16) & 1u)) >> 16;
    return (u16)r;
}
__device__ __forceinline__ float sigmoidf_(float x) { return 1.0f / (1.0f + __expf(-x)); }
__device__ __forceinline__ float tanhf_(float x) { return 1.0f - 2.0f / (__expf(2.0f * x) + 1.0f); }

// ---------------- precompute kernel ----------------
__global__ __launch_bounds__(256) void ggnn_pre(
    const int* __restrict__ node_slice, const int* __restrict__ type_slice,
    const float* __restrict__ emb_table, const float* __restrict__ type_table,
    const float* __restrict__ W_in,
    const float* __restrict__ Wr, const float* __restrict__ br,
    const float* __restrict__ Wz, const float* __restrict__ bz,
    const float* __restrict__ Wt, const float* __restrict__ bt,
    float* __restrict__ NT, float* __restrict__ Hws)
{
    int b = blockIdx.x >> 3;
    int chunk = blockIdx.x & 7;
    int t = threadIdx.x;
    __shared__ float now[96];
    for (int ii = 0; ii < 16; ++ii) {
        int i = chunk * 16 + ii;
        if (t < 32) now[t] = type_table[type_slice[b * N_ + i] * 32 + t];
        else if (t < 96) now[t] = emb_table[node_slice[b * N_ + i] * 64 + (t - 32)];
        __syncthreads();
        if (t < 192) {
            int m = t >> 6, e = t & 63;
            const float* W  = (m == 0) ? Wr : (m == 1) ? Wz : Wt;
            const float* bb = (m == 0) ? br : (m == 1) ? bz : bt;
            float acc = bb[e];
            #pragma unroll
            for (int k = 0; k < 96; ++k) acc += now[k] * W[k * 64 + e];
            NT[(b * N_ + i) * 192 + m * 64 + e] = acc;
        } else {
            int e = t - 192;
            float acc = 0.f;
            #pragma unroll
            for (int k = 0; k < 64; ++k) acc += now[32 + k] * W_in[k * 64 + e];
            Hws[(b * N_ + i) * 64 + e] = acc;
        }
        __syncthreads();
    }
}

// ---------------- main scan kernel ----------------
__global__ __launch_bounds__(256) void ggnn_main(
    const int* __restrict__ node_slice, const int* __restrict__ rel_matrix,
    const int* __restrict__ input_length, const float* __restrict__ distance,
    const float* __restrict__ emb_table, const float* __restrict__ rel_table,
    const float* __restrict__ W_in, const float* __restrict__ b_in,
    const float* __restrict__ Wr, const float* __restrict__ Wz, const float* __restrict__ Wt,
    const float* __restrict__ W_co, const float* __restrict__ b_co,
    const float* __restrict__ W1, const float* __restrict__ b1,
    const float* __restrict__ W2, const float* __restrict__ b2,
    const float* __restrict__ W3, const float* __restrict__ b3,
    const float* __restrict__ W4, const float* __restrict__ b4,
    const float* __restrict__ NT, const float* __restrict__ Hws,
    float* __restrict__ out)
{
    __shared__ __align__(16) float H[N_ * 64];   // 32 KB, hidden @ W_in_top cache (f32)
    __shared__ u16 hid[N_ * 64];                 // 16 KB, hidden state (bf16)
    __shared__ u16 relWb[51 * 64];               // 6.5 KB, b_in + rel_table @ W_in_bot (bf16)
    __shared__ float disc[N_];
    __shared__ int   relrow[N_];
    __shared__ float pmax[4][64];
    __shared__ int   anyflag[4];
    __shared__ float dis_pre[64];
    __shared__ float r_row[64];
    __shared__ float z_row[64];
    __shared__ float subS[64];
    __shared__ float temp[192];
    __shared__ float h1[128];
    __shared__ float h2v[64];
    __shared__ float h3v[32];

    const int b = blockIdx.x;
    const int t = threadIdx.x;
    const int w = t >> 6;
    const int e = t & 63;
    const int len = input_length[b];
    const float NEGINF = -__builtin_inff();

    // ---- prologue ----
    if (t < N_) disc[t] = -0.1f * distance[b * N_ + t];

    for (int idx = t; idx < N_ * 64; idx += 256) {
        int j = idx >> 6, ee = idx & 63;
        hid[idx] = f2b(emb_table[node_slice[b * N_ + j] * 64 + ee]);
    }
    {
        const float4* src = (const float4*)(Hws + b * N_ * 64);
        float4* dst = (float4*)H;
        for (int idx = t; idx < N_ * 16; idx += 256) dst[idx] = src[idx];
    }
    for (int idx = t; idx < 51 * 64; idx += 256) {
        int v = idx >> 6, ee = idx & 63;
        float acc = b_in[ee];
        #pragma unroll
        for (int k = 0; k < 32; ++k)
            acc += rel_table[v * 32 + k] * W_in[(64 + k) * 64 + ee];
        relWb[idx] = f2b(acc);
    }
    // per-lane weight column registers
    float wcol[64];
    {
        const float* wsrc = (w == 0) ? (Wr + 96 * 64) : (w == 1) ? (Wz + 96 * 64)
                          : (w == 2) ? (Wt + 96 * 64) : W_in;
        #pragma unroll
        for (int k = 0; k < 64; ++k) wcol[k] = wsrc[k * 64 + e];
    }
    __syncthreads();

    const float* NTb = NT + b * N_ * 192;

    // ---- scan ----
    for (int i = 0; i < len; ++i) {
        if (t < N_) relrow[t] = rel_matrix[(b * N_ + i) * N_ + t];
        __syncthreads();                                   // A (also guards prev H[i-1] write)

        float m = NEGINF;
        int any = 0;
        const int jend = min(len, w * 32 + 32);
        for (int j = w * 32; j < jend; ++j) {
            int r = relrow[j];
            if (r != 0) {
                float pre = H[j * 64 + e] + b2f(relWb[r * 64 + e]);
                pre = fmaxf(pre, 0.f) * disc[j];
                m = fmaxf(m, pre);
                any = 1;
            }
        }
        pmax[w][e] = m;
        if (e == 0) anyflag[w] = any;
        __syncthreads();                                   // B

        if (w == 0) {
            float dp = fmaxf(fmaxf(pmax[0][e], pmax[1][e]), fmaxf(pmax[2][e], pmax[3][e]));
            int anyv = anyflag[0] | anyflag[1] | anyflag[2] | anyflag[3];
            dis_pre[e] = anyv ? dp : 0.f;
        }
        float ntv = (w < 3) ? NTb[i * 192 + w * 64 + e] : 0.f;
        __syncthreads();                                   // C

        if (w == 0) {
            float acc = ntv;
            #pragma unroll
            for (int k = 0; k < 64; ++k) acc += dis_pre[k] * wcol[k];
            r_row[e] = sigmoidf_(acc);
        } else if (w == 1) {
            float acc = ntv;
            #pragma unroll
            for (int k = 0; k < 64; ++k) acc += dis_pre[k] * wcol[k];
            z_row[e] = sigmoidf_(acc);
        }
        __syncthreads();                                   // D

        if (w == 2) {
            float acc = ntv;
            #pragma unroll
            for (int k = 0; k < 64; ++k) acc += r_row[k] * dis_pre[k] * wcol[k];
            float hh = tanhf_(acc);
            float z = z_row[e];
            float upd = (1.f - z) * dis_pre[e] + z * hh;
            hid[i * 64 + e] = f2b(upd);
        }
        __syncthreads();                                   // E

        if (w == 3) {
            float acc = 0.f;
            #pragma unroll
            for (int k = 0; k < 64; ++k) acc += b2f(hid[i * 64 + k]) * wcol[k];
            H[i * 64 + e] = acc;
        }
        // next iteration's barrier A guards the H[i] write
    }
    __syncthreads();

    // ---- epilogue ----
    {
        float s = NEGINF;
        const int jend = min(len, w * 32 + 32);
        for (int j = w * 32; j < jend; ++j) s = fmaxf(s, b2f(hid[j * 64 + e]));
        pmax[w][e] = s;
    }
    __syncthreads();
    if (w == 0)
        subS[e] = fmaxf(fmaxf(pmax[0][e], pmax[1][e]), fmaxf(pmax[2][e], pmax[3][e]));
    __syncthreads();

    if (t < 128) {
        const int half = t >> 6;                    // 0: ua(user=row 0), 1: ia(item=row len-1)
        const int row = (half == 0) ? 0 : (len - 1);
        float acc = b_co[e];
        #pragma unroll
        for (int k = 0; k < 64; ++k) acc += b2f(hid[row * 64 + k]) * W_co[k * 64 + e];
        #pragma unroll
        for (int k = 0; k < 64; ++k) acc += subS[k] * W_co[(64 + k) * 64 + e];
        float act = fmaxf(acc, 0.f);
        float self = b2f(hid[row * 64 + e]);
        temp[half * 128 + e] = act * self;          // [0:64]=ua*user, [128:192]=ia*item
    } else if (t < 192) {
        temp[64 + (t - 128)] = subS[t - 128];       // [64:128]=sub
    }
    __syncthreads();

    if (t < 128) {
        float acc = b1[t];
        for (int k = 0; k < 192; ++k) acc += temp[k] * W1[k * 128 + t];
        h1[t] = fmaxf(acc, 0.f);
    }
    __syncthreads();
    if (t < 64) {
        float acc = b2[t];
        for (int k = 0; k < 128; ++k) acc += h1[k] * W2[k * 64 + t];
        h2v[t] = fmaxf(acc, 0.f);
    }
    __syncthreads();
    if (t < 32) {
        float acc = b3[t];
        for (int k = 0; k < 64; ++k) acc += h2v[k] * W3[k * 32 + t];
        h3v[t] = fmaxf(acc, 0.f);
    }
    __syncthreads();
    if (t == 0) {
        float acc = b4[0];
        for (int k = 0; k < 32; ++k) acc += h3v[k] * W4[k];
        out[b] = sigmoidf_(acc);
    }
}

extern "C" void kernel_launch(void* const* d_in, const int* in_sizes, int n_in,
                              void* d_out, int out_size, void* d_ws, size_t ws_size,
                              hipStream_t stream)
{
    const int*   node_slice = (const int*)d_in[0];
    const int*   type_slice = (const int*)d_in[1];
    const float* distance   = (const float*)d_in[2];
    const int*   rel_matrix = (const int*)d_in[3];
    const int*   input_len  = (const int*)d_in[4];
    // d_in[5] = isBatch (ignored)
    const float* emb_table  = (const float*)d_in[6];
    const float* type_table = (const float*)d_in[7];
    const float* rel_table  = (const float*)d_in[8];
    const float* W_in = (const float*)d_in[9];  const float* b_in = (const float*)d_in[10];
    const float* Wr   = (const float*)d_in[11]; const float* br   = (const float*)d_in[12];
    const float* Wz   = (const float*)d_in[13]; const float* bz   = (const float*)d_in[14];
    const float* Wt   = (const float*)d_in[15]; const float* bt   = (const float*)d_in[16];
    const float* W_co = (const float*)d_in[17]; const float* b_co = (const float*)d_in[18];
    const float* W1   = (const float*)d_in[19]; const float* b1   = (const float*)d_in[20];
    const float* W2   = (const float*)d_in[21]; const float* b2   = (const float*)d_in[22];
    const float* W3   = (const float*)d_in[23]; const float* b3   = (const float*)d_in[24];
    const float* W4   = (const float*)d_in[25]; const float* b4   = (const float*)d_in[26];

    float* NT  = (float*)d_ws;                  // 128*128*192 f32 = 12.58 MB
    float* Hws = NT + B_ * N_ * 192;            // 128*128*64  f32 =  4.19 MB

    ggnn_pre<<<dim3(1024), dim3(256), 0, stream>>>(
        node_slice, type_slice, emb_table, type_table,
        W_in, Wr, br, Wz, bz, Wt, bt, NT, Hws);

    ggnn_main<<<dim3(B_), dim3(256), 0, stream>>>(
        node_slice, rel_matrix, input_len, distance, emb_table, rel_table,
        W_in, b_in, Wr, Wz, Wt, W_co, b_co,
        W1, b1, W2, b2, W3, b3, W4, b4,
        NT, Hws, (float*)d_out);
}

// Round 3
// 1118.216 us; speedup vs baseline: 1.3185x; 1.3185x over previous
//
#include <hip/hip_runtime.h>
#include <hip/hip_bf16.h>

// GGNN fused scan, latency-optimized. B=128, N=128, E=64, T=32, R=32.
//  - ggnn_pre: NT[b,i,{r,z,t},e], Hws[b,j,e] -> d_ws (16.8 MB f32).
//  - ggnn_main: 1 block/batch, 256 thr (4 waves), 3 barriers/step:
//      A: relrow publish; B: pmax ready; E: upd row ready.
//    wave0 = all gates (r,z,t,upd; 192 wcol regs, LDS broadcast matvecs),
//    wave3 = H-row update (64 wcol regs), waves1/2 only help max phase.
//    rel-row + NT prefetched one step ahead (issued right after A).
//    H transposed (stride 132, b128 over j), relWb transposed (stride 53).
//    user/item/sub tracked incrementally -> no hidden-state array at all.

#define B_ 128
#define N_ 128

__device__ __forceinline__ float sigmoidf_(float x) { return 1.0f / (1.0f + __expf(-x)); }
__device__ __forceinline__ float tanhf_(float x) { return 1.0f - 2.0f / (__expf(2.0f * x) + 1.0f); }

// ---------------- precompute kernel ----------------
__global__ __launch_bounds__(256) void ggnn_pre(
    const int* __restrict__ node_slice, const int* __restrict__ type_slice,
    const float* __restrict__ emb_table, const float* __restrict__ type_table,
    const float* __restrict__ W_in,
    const float* __restrict__ Wr, const float* __restrict__ br,
    const float* __restrict__ Wz, const float* __restrict__ bz,
    const float* __restrict__ Wt, const float* __restrict__ bt,
    float* __restrict__ NT, float* __restrict__ Hws)
{
    int b = blockIdx.x >> 3;
    int chunk = blockIdx.x & 7;
    int t = threadIdx.x;
    __shared__ float now[96];
    for (int ii = 0; ii < 16; ++ii) {
        int i = chunk * 16 + ii;
        if (t < 32) now[t] = type_table[type_slice[b * N_ + i] * 32 + t];
        else if (t < 96) now[t] = emb_table[node_slice[b * N_ + i] * 64 + (t - 32)];
        __syncthreads();
        if (t < 192) {
            int m = t >> 6, e = t & 63;
            const float* W  = (m == 0) ? Wr : (m == 1) ? Wz : Wt;
            const float* bb = (m == 0) ? br : (m == 1) ? bz : bt;
            float acc = bb[e];
            #pragma unroll
            for (int k = 0; k < 96; ++k) acc += now[k] * W[k * 64 + e];
            NT[(b * N_ + i) * 192 + m * 64 + e] = acc;
        } else {
            int e = t - 192;
            float acc = 0.f;
            #pragma unroll
            for (int k = 0; k < 64; ++k) acc += now[32 + k] * W_in[k * 64 + e];
            Hws[(b * N_ + i) * 64 + e] = acc;
        }
        __syncthreads();
    }
}

// ---------------- main scan kernel ----------------
#define HT_S 132   // H_T row stride (floats): 16B aligned, bank-uniform for b128
#define RW_S 53    // relWb_T row stride: odd -> conflict-free scattered reads

__global__ __launch_bounds__(256, 1) void ggnn_main(
    const int* __restrict__ rel_matrix,
    const int* __restrict__ input_length, const float* __restrict__ distance,
    const float* __restrict__ rel_table,
    const float* __restrict__ W_in, const float* __restrict__ b_in,
    const float* __restrict__ Wr, const float* __restrict__ Wz, const float* __restrict__ Wt,
    const float* __restrict__ W_co, const float* __restrict__ b_co,
    const float* __restrict__ W1, const float* __restrict__ b1,
    const float* __restrict__ W2, const float* __restrict__ b2,
    const float* __restrict__ W3, const float* __restrict__ b3,
    const float* __restrict__ W4, const float* __restrict__ b4,
    const float* __restrict__ NT, const float* __restrict__ Hws,
    float* __restrict__ out)
{
    __shared__ __align__(16) float H_T[64 * HT_S];      // 33792 B
    __shared__ __align__(16) float relWb_T[64 * RW_S];  // 13568 B
    __shared__ __align__(16) float disc[N_];
    __shared__ __align__(16) int   relrow[N_];
    __shared__ __align__(16) float pmax[256];
    __shared__ __align__(16) float dprow[64];
    __shared__ __align__(16) float rdprow[64];
    __shared__ __align__(16) float updrow[64];
    __shared__ __align__(16) float userrow[64];
    __shared__ __align__(16) float itemrow[64];
    __shared__ __align__(16) float submrow[64];
    __shared__ __align__(16) float temp[192];
    __shared__ float h1[128];
    __shared__ float h2v[64];
    __shared__ float h3v[32];

    const int b = blockIdx.x;
    const int t = threadIdx.x;
    const int w = t >> 6;
    const int e = t & 63;
    const int len = input_length[b];
    const float NEGINF = -__builtin_inff();

    // ---- prologue ----
    if (t < N_) disc[t] = -0.1f * distance[b * N_ + t];

    for (int idx = t; idx < N_ * 64; idx += 256) {       // H_T <- Hws (transposed)
        int j = idx >> 6, ee = idx & 63;
        H_T[ee * HT_S + j] = Hws[b * N_ * 64 + idx];
    }
    for (int idx = t; idx < 51 * 64; idx += 256) {       // relWb_T = b_in + rel@W_in_bot
        int r = idx >> 6, ee = idx & 63;
        float acc = b_in[ee];
        #pragma unroll
        for (int k = 0; k < 32; ++k)
            acc += rel_table[r * 32 + k] * W_in[(64 + k) * 64 + ee];
        relWb_T[ee * RW_S + r] = acc;
    }

    // per-lane weight columns
    float wr[64], wz[64], wt[64], win[64];
    if (w == 0) {
        #pragma unroll
        for (int k = 0; k < 64; ++k) {
            wr[k] = Wr[(96 + k) * 64 + e];
            wz[k] = Wz[(96 + k) * 64 + e];
            wt[k] = Wt[(96 + k) * 64 + e];
        }
    } else if (w == 3) {
        #pragma unroll
        for (int k = 0; k < 64; ++k) win[k] = W_in[k * 64 + e];
    }

    // prefetch step 0
    int rel_pf = 0;
    float ntr_c = 0.f, ntz_c = 0.f, ntt_c = 0.f;
    if (t < N_) rel_pf = (t < len) ? rel_matrix[(b * N_) * N_ + t] : 0;
    if (w == 0) {
        const float* NTp = NT + (b * N_) * 192;
        ntr_c = NTp[e]; ntz_c = NTp[64 + e]; ntt_c = NTp[128 + e];
    }
    float subm_r = NEGINF, upd_last = 0.f;
    __syncthreads();

    // ---- scan ----
    for (int i = 0; i < len; ++i) {
        if (t < N_) relrow[t] = rel_pf;
        __syncthreads();                                 // A (relrow + prev H_T[.,i-1])

        // prefetch step i+1 (consumed next step; latency hidden by this step)
        float ntr_p = 0.f, ntz_p = 0.f, ntt_p = 0.f;
        {
            const int ip = (i + 1) & (N_ - 1);
            if (t < N_) rel_pf = (t < len) ? rel_matrix[(b * N_ + ip) * N_ + t] : 0;
            if (w == 0) {
                const float* NTp = NT + (b * N_ + ip) * 192;
                ntr_p = NTp[e]; ntz_p = NTp[64 + e]; ntt_p = NTp[128 + e];
            }
        }

        // ---- max phase: branchless, batched LDS reads ----
        float m = NEGINF;
        const float* hcol = H_T + e * HT_S;
        const float* qrow = relWb_T + e * RW_S;
        #pragma unroll
        for (int g = 0; g < 8; ++g) {
            const int j0 = w * 32 + g * 4;
            const int4   rr = *(const int4*)(relrow + j0);
            const float4 dd = *(const float4*)(disc + j0);
            const float4 hv = *(const float4*)(hcol + j0);
            float q0 = qrow[rr.x], q1 = qrow[rr.y], q2 = qrow[rr.z], q3 = qrow[rr.w];
            float s0 = fmaxf(hv.x + q0, 0.f) * dd.x;
            float s1 = fmaxf(hv.y + q1, 0.f) * dd.y;
            float s2 = fmaxf(hv.z + q2, 0.f) * dd.z;
            float s3 = fmaxf(hv.w + q3, 0.f) * dd.w;
            m = (rr.x != 0) ? fmaxf(m, s0) : m;
            m = (rr.y != 0) ? fmaxf(m, s1) : m;
            m = (rr.z != 0) ? fmaxf(m, s2) : m;
            m = (rr.w != 0) ? fmaxf(m, s3) : m;
        }
        pmax[w * 64 + e] = m;
        __syncthreads();                                 // B

        if (w == 0) {
            float dp = fmaxf(fmaxf(pmax[e], pmax[64 + e]),
                             fmaxf(pmax[128 + e], pmax[192 + e]));
            float dis0 = (dp == NEGINF) ? 0.f : dp;
            dprow[e] = dis0;
            // r/z matvecs off one broadcast read stream (same-wave LDS in-order)
            float accr = ntr_c, accz = ntz_c;
            const float4* dp4 = (const float4*)dprow;
            #pragma unroll
            for (int g = 0; g < 16; ++g) {
                float4 v = dp4[g];
                accr += v.x * wr[4*g] + v.y * wr[4*g+1] + v.z * wr[4*g+2] + v.w * wr[4*g+3];
                accz += v.x * wz[4*g] + v.y * wz[4*g+1] + v.z * wz[4*g+2] + v.w * wz[4*g+3];
            }
            float r = sigmoidf_(accr);
            float z = sigmoidf_(accz);
            rdprow[e] = r * dis0;
            float acct = ntt_c;
            const float4* rd4 = (const float4*)rdprow;
            #pragma unroll
            for (int g = 0; g < 16; ++g) {
                float4 v = rd4[g];
                acct += v.x * wt[4*g] + v.y * wt[4*g+1] + v.z * wt[4*g+2] + v.w * wt[4*g+3];
            }
            float hh = tanhf_(acct);
            float upd = (1.f - z) * dis0 + z * hh;
            updrow[e] = upd;
            if (i == 0) userrow[e] = upd;
            subm_r = fmaxf(subm_r, upd);
            upd_last = upd;
            ntr_c = ntr_p; ntz_c = ntz_p; ntt_c = ntt_p;
        }
        __syncthreads();                                 // E (updrow ready)

        if (w == 3) {
            float acc = 0.f;
            const float4* up4 = (const float4*)updrow;
            #pragma unroll
            for (int g = 0; g < 16; ++g) {
                float4 v = up4[g];
                acc += v.x * win[4*g] + v.y * win[4*g+1] + v.z * win[4*g+2] + v.w * win[4*g+3];
            }
            H_T[e * HT_S + i] = acc;                     // guarded by next A
        }
    }

    if (w == 0) { itemrow[e] = upd_last; submrow[e] = subm_r; }
    __syncthreads();

    // ---- epilogue ----
    if (t < 128) {
        const int half = t >> 6;                // 0: ua*user, 1: ia*item
        const float* row = (half == 0) ? userrow : itemrow;
        float acc = b_co[e];
        #pragma unroll
        for (int k = 0; k < 64; ++k) acc += row[k] * W_co[k * 64 + e];
        #pragma unroll
        for (int k = 0; k < 64; ++k) acc += submrow[k] * W_co[(64 + k) * 64 + e];
        float act = fmaxf(acc, 0.f);
        temp[half * 128 + e] = act * row[e];
    } else if (t < 192) {
        temp[64 + (t - 128)] = submrow[t - 128];
    }
    __syncthreads();

    if (t < 128) {
        float acc = b1[t];
        for (int k = 0; k < 192; ++k) acc += temp[k] * W1[k * 128 + t];
        h1[t] = fmaxf(acc, 0.f);
    }
    __syncthreads();
    if (t < 64) {
        float acc = b2[t];
        for (int k = 0; k < 128; ++k) acc += h1[k] * W2[k * 64 + t];
        h2v[t] = fmaxf(acc, 0.f);
    }
    __syncthreads();
    if (t < 32) {
        float acc = b3[t];
        for (int k = 0; k < 64; ++k) acc += h2v[k] * W3[k * 32 + t];
        h3v[t] = fmaxf(acc, 0.f);
    }
    __syncthreads();
    if (t == 0) {
        float acc = b4[0];
        for (int k = 0; k < 32; ++k) acc += h3v[k] * W4[k];
        out[b] = sigmoidf_(acc);
    }
}

extern "C" void kernel_launch(void* const* d_in, const int* in_sizes, int n_in,
                              void* d_out, int out_size, void* d_ws, size_t ws_size,
                              hipStream_t stream)
{
    const int*   node_slice = (const int*)d_in[0];
    const int*   type_slice = (const int*)d_in[1];
    const float* distance   = (const float*)d_in[2];
    const int*   rel_matrix = (const int*)d_in[3];
    const int*   input_len  = (const int*)d_in[4];
    // d_in[5] = isBatch (ignored)
    const float* emb_table  = (const float*)d_in[6];
    const float* type_table = (const float*)d_in[7];
    const float* rel_table  = (const float*)d_in[8];
    const float* W_in = (const float*)d_in[9];  const float* b_in = (const float*)d_in[10];
    const float* Wr   = (const float*)d_in[11]; const float* br   = (const float*)d_in[12];
    const float* Wz   = (const float*)d_in[13]; const float* bz   = (const float*)d_in[14];
    const float* Wt   = (const float*)d_in[15]; const float* bt   = (const float*)d_in[16];
    const float* W_co = (const float*)d_in[17]; const float* b_co = (const float*)d_in[18];
    const float* W1   = (const float*)d_in[19]; const float* b1   = (const float*)d_in[20];
    const float* W2   = (const float*)d_in[21]; const float* b2   = (const float*)d_in[22];
    const float* W3   = (const float*)d_in[23]; const float* b3   = (const float*)d_in[24];
    const float* W4   = (const float*)d_in[25]; const float* b4   = (const float*)d_in[26];

    float* NT  = (float*)d_ws;                  // 128*128*192 f32 = 12.58 MB
    float* Hws = NT + B_ * N_ * 192;            // 128*128*64  f32 =  4.19 MB

    ggnn_pre<<<dim3(1024), dim3(256), 0, stream>>>(
        node_slice, type_slice, emb_table, type_table,
        W_in, Wr, br, Wz, bz, Wt, bt, NT, Hws);

    ggnn_main<<<dim3(B_), dim3(256), 0, stream>>>(
        rel_matrix, input_len, distance, rel_table,
        W_in, b_in, Wr, Wz, Wt, W_co, b_co,
        W1, b1, W2, b2, W3, b3, W4, b4,
        NT, Hws, (float*)d_out);
}

// Round 4
// 520.774 us; speedup vs baseline: 2.8312x; 2.1472x over previous
//
#include <hip/hip_runtime.h>
#include <hip/hip_bf16.h>

// GGNN fused scan v3. B=128, N=128, E=64, T=32, R=32.
// ggnn_pre: 512 blocks (b, quarter): stage 32 now-rows in LDS, per-lane weight
//   columns in regs (96 VGPR), 32 broadcast matvecs -> NT + Hws in d_ws.
// ggnn_main: 1 block/batch, 256 thr, 4 barriers/step. ONE wcol[64] per thread
//   (no spill): w0=r-gate, w1=z-gate, w2=t-gate+upd (+user/item/sub track),
//   w3=H-row update. H stored XOR-swizzled (conflict-free aligned b128).
//   rel-row + NT prefetched one step ahead. Steps i>=len are exact no-ops.

#define B_ 128
#define N_ 128
#define SW(ee) (((ee) & 7) << 2)   // XOR swizzle for H: phys_j = j ^ SW(e)
#define RW_S 53                    // relWb stride (odd -> conflict-free gathers)

__device__ __forceinline__ float sigmoidf_(float x) { return 1.0f / (1.0f + __expf(-x)); }
__device__ __forceinline__ float tanhf_(float x) { return 1.0f - 2.0f / (__expf(2.0f * x) + 1.0f); }

// ---------------- precompute kernel ----------------
__global__ __launch_bounds__(256, 2) void ggnn_pre(
    const int* __restrict__ node_slice, const int* __restrict__ type_slice,
    const float* __restrict__ emb_table, const float* __restrict__ type_table,
    const float* __restrict__ W_in,
    const float* __restrict__ Wr, const float* __restrict__ br,
    const float* __restrict__ Wz, const float* __restrict__ bz,
    const float* __restrict__ Wt, const float* __restrict__ bt,
    float* __restrict__ NT, float* __restrict__ Hws)
{
    const int b = blockIdx.x >> 2;
    const int i0 = (blockIdx.x & 3) * 32;
    const int t = threadIdx.x;
    const int w = t >> 6;
    const int e = t & 63;

    __shared__ int   tsL[32], nsL[32];
    __shared__ __align__(16) float now[32 * 96];   // 12 KB

    if (t < 32) tsL[t] = type_slice[b * N_ + i0 + t];
    else if (t < 64) nsL[t - 32] = node_slice[b * N_ + i0 + (t - 32)];
    __syncthreads();

    for (int idx = t; idx < 32 * 96; idx += 256) {
        int i = idx / 96, c = idx - i * 96;
        now[idx] = (c < 32) ? type_table[tsL[i] * 32 + c]
                            : emb_table[nsL[i] * 64 + (c - 32)];
    }

    float wc[96];
    float bias;
    if (w < 3) {
        const float* W  = (w == 0) ? Wr : (w == 1) ? Wz : Wt;
        const float* bb = (w == 0) ? br : (w == 1) ? bz : bt;
        bias = bb[e];
        #pragma unroll
        for (int k = 0; k < 96; ++k) wc[k] = W[k * 64 + e];
    } else {
        bias = 0.f;
        #pragma unroll
        for (int k = 0; k < 64; ++k) wc[k] = W_in[k * 64 + e];
        #pragma unroll
        for (int k = 64; k < 96; ++k) wc[k] = 0.f;
    }
    __syncthreads();

    if (w < 3) {
        for (int i = 0; i < 32; ++i) {
            const float4* nv = (const float4*)(now + i * 96);
            float acc = bias;
            #pragma unroll
            for (int g = 0; g < 24; ++g) {
                float4 v = nv[g];
                acc += v.x * wc[4*g] + v.y * wc[4*g+1] + v.z * wc[4*g+2] + v.w * wc[4*g+3];
            }
            NT[(b * N_ + i0 + i) * 192 + w * 64 + e] = acc;
        }
    } else {
        for (int i = 0; i < 32; ++i) {
            const float4* nv = (const float4*)(now + i * 96);
            float acc = 0.f;
            #pragma unroll
            for (int g = 0; g < 16; ++g) {
                float4 v = nv[g];
                acc += v.x * wc[4*g] + v.y * wc[4*g+1] + v.z * wc[4*g+2] + v.w * wc[4*g+3];
            }
            Hws[(b * N_ + i0 + i) * 64 + e] = acc;
        }
    }
}

// ---------------- main scan kernel ----------------
__global__ __launch_bounds__(256, 1) void ggnn_main(
    const int* __restrict__ rel_matrix,
    const int* __restrict__ input_length, const float* __restrict__ distance,
    const float* __restrict__ rel_table,
    const float* __restrict__ W_in, const float* __restrict__ b_in,
    const float* __restrict__ Wr, const float* __restrict__ Wz, const float* __restrict__ Wt,
    const float* __restrict__ W_co, const float* __restrict__ b_co,
    const float* __restrict__ W1, const float* __restrict__ b1,
    const float* __restrict__ W2, const float* __restrict__ b2,
    const float* __restrict__ W3, const float* __restrict__ b3,
    const float* __restrict__ W4, const float* __restrict__ b4,
    const float* __restrict__ NT, const float* __restrict__ Hws,
    float* __restrict__ out)
{
    __shared__ __align__(16) float H_sw[64 * 128];        // 32 KB, XOR-swizzled
    __shared__ __align__(16) float relWb[64 * RW_S];      // 13.25 KB
    __shared__ __align__(16) float disc[N_];
    __shared__ __align__(16) int   relrow[N_];
    __shared__ __align__(16) float pmax[256];
    __shared__ __align__(16) float dp0[64], dp1[64], dp2[64];
    __shared__ __align__(16) float r_row[64], z_row[64], updrow[64];
    __shared__ __align__(16) float userrow[64], itemrow[64], submrow[64];
    __shared__ __align__(16) float temp[192];
    __shared__ float h1[128];
    __shared__ float h2v[64];
    __shared__ float h3v[32];

    const int b = blockIdx.x;
    const int t = threadIdx.x;
    const int w = t >> 6;
    const int e = t & 63;
    const int len = input_length[b];
    const float NEGINF = -__builtin_inff();

    // ---- prologue ----
    if (t < N_) disc[t] = -0.1f * distance[b * N_ + t];

    for (int idx = t; idx < N_ * 64; idx += 256) {        // H_sw <- Hws
        int ee = idx & 63, j = idx >> 6;
        H_sw[(ee << 7) + (j ^ SW(ee))] = Hws[b * N_ * 64 + idx];
    }
    for (int idx = t; idx < 51 * 64; idx += 256) {        // relWb = b_in + rel@W_in_bot
        int r = idx >> 6, ee = idx & 63;
        float acc = b_in[ee];
        #pragma unroll
        for (int k = 0; k < 32; ++k)
            acc += rel_table[r * 32 + k] * W_in[(64 + k) * 64 + ee];
        relWb[ee * RW_S + r] = acc;
    }

    // ONE per-lane weight column (no spill): w0=Wr_bot, w1=Wz_bot, w2=Wt_bot, w3=W_in_top
    float wcol[64];
    {
        const float* wsrc = (w == 0) ? (Wr + 96 * 64) : (w == 1) ? (Wz + 96 * 64)
                          : (w == 2) ? (Wt + 96 * 64) : W_in;
        #pragma unroll
        for (int k = 0; k < 64; ++k) wcol[k] = wsrc[k * 64 + e];
    }

    // prefetch step 0
    float nt_c = 0.f;
    if (t < N_) relrow[t] = (t < len) ? rel_matrix[(b * N_) * N_ + t] : 0;
    if (w < 3) nt_c = NT[(b * N_) * 192 + w * 64 + e];
    float user_r = 0.f, item_r = 0.f, subm_r = NEGINF;
    __syncthreads();                                      // A0

    const int sw = SW(e);
    const float* hrow = H_sw + (e << 7);

    // ---- scan ----
    for (int i = 0; i < len; ++i) {
        // prefetch step i+1 (drained by barrier B, ~1 max-phase later)
        const int ip = (i + 1) & (N_ - 1);
        int rel_p = 0; float nt_p = 0.f;
        if (t < N_) rel_p = (t < len) ? rel_matrix[(b * N_ + ip) * N_ + t] : 0;
        if (w < 3) nt_p = NT[(b * N_ + ip) * 192 + w * 64 + e];

        // ---- max phase (all 4 waves, 32 j each) ----
        float m = NEGINF;
        #pragma unroll
        for (int g = 0; g < 8; ++g) {
            const int jj = w * 32 + 4 * g;
            const int4   rr = *(const int4*)(relrow + jj);     // broadcast
            const float4 dd = *(const float4*)(disc + jj);     // broadcast
            const float4 hv = *(const float4*)(hrow + (jj ^ sw)); // conflict-free
            float q0 = relWb[e * RW_S + rr.x];
            float q1 = relWb[e * RW_S + rr.y];
            float q2 = relWb[e * RW_S + rr.z];
            float q3 = relWb[e * RW_S + rr.w];
            float s0 = fmaxf(hv.x + q0, 0.f) * dd.x;
            float s1 = fmaxf(hv.y + q1, 0.f) * dd.y;
            float s2 = fmaxf(hv.z + q2, 0.f) * dd.z;
            float s3 = fmaxf(hv.w + q3, 0.f) * dd.w;
            m = (rr.x != 0) ? fmaxf(m, s0) : m;
            m = (rr.y != 0) ? fmaxf(m, s1) : m;
            m = (rr.z != 0) ? fmaxf(m, s2) : m;
            m = (rr.w != 0) ? fmaxf(m, s3) : m;
        }
        pmax[t] = m;
        __syncthreads();                                  // B

        float dp = fmaxf(fmaxf(pmax[e], pmax[64 + e]),
                         fmaxf(pmax[128 + e], pmax[192 + e]));
        float dis0 = (dp == NEGINF) ? 0.f : dp;

        if (w == 0) {                                     // r-gate
            dp0[e] = dis0;
            float acc = nt_c;
            const float4* v4 = (const float4*)dp0;        // same-wave in-order
            #pragma unroll
            for (int g = 0; g < 16; ++g) {
                float4 v = v4[g];
                acc += v.x * wcol[4*g] + v.y * wcol[4*g+1] + v.z * wcol[4*g+2] + v.w * wcol[4*g+3];
            }
            r_row[e] = sigmoidf_(acc);
        } else if (w == 1) {                              // z-gate
            dp1[e] = dis0;
            float acc = nt_c;
            const float4* v4 = (const float4*)dp1;
            #pragma unroll
            for (int g = 0; g < 16; ++g) {
                float4 v = v4[g];
                acc += v.x * wcol[4*g] + v.y * wcol[4*g+1] + v.z * wcol[4*g+2] + v.w * wcol[4*g+3];
            }
            z_row[e] = sigmoidf_(acc);
        } else if (w == 2) {
            dp2[e] = dis0;
        }
        __syncthreads();                                  // C (r_row, z_row ready)

        if (w == 2) {                                     // t-gate + update
            float acc = nt_c;
            const float4* rv4 = (const float4*)r_row;
            const float4* dv4 = (const float4*)dp2;
            #pragma unroll
            for (int g = 0; g < 16; ++g) {
                float4 rv = rv4[g];
                float4 dv = dv4[g];
                acc += rv.x * dv.x * wcol[4*g]   + rv.y * dv.y * wcol[4*g+1]
                     + rv.z * dv.z * wcol[4*g+2] + rv.w * dv.w * wcol[4*g+3];
            }
            float hh = tanhf_(acc);
            float z = z_row[e];
            float upd = (1.f - z) * dis0 + z * hh;
            updrow[e] = upd;
            if (i == 0) user_r = upd;
            subm_r = fmaxf(subm_r, upd);
            item_r = upd;
        }
        __syncthreads();                                  // D (updrow ready)

        if (w == 3) {                                     // H-row update
            float acc = 0.f;
            const float4* v4 = (const float4*)updrow;
            #pragma unroll
            for (int g = 0; g < 16; ++g) {
                float4 v = v4[g];
                acc += v.x * wcol[4*g] + v.y * wcol[4*g+1] + v.z * wcol[4*g+2] + v.w * wcol[4*g+3];
            }
            H_sw[(e << 7) + (i ^ sw)] = acc;
        } else if (t < N_) {
            relrow[t] = rel_p;                            // restage for step i+1
        }
        nt_c = nt_p;
        __syncthreads();                                  // A (H + relrow ready)
    }

    if (w == 2) { userrow[e] = user_r; itemrow[e] = item_r; submrow[e] = subm_r; }
    __syncthreads();

    // ---- epilogue ----
    if (t < 128) {
        const int half = t >> 6;                // 0: ua*user, 1: ia*item
        const float* row = (half == 0) ? userrow : itemrow;
        float acc = b_co[e];
        #pragma unroll
        for (int k = 0; k < 64; ++k) acc += row[k] * W_co[k * 64 + e];
        #pragma unroll
        for (int k = 0; k < 64; ++k) acc += submrow[k] * W_co[(64 + k) * 64 + e];
        float act = fmaxf(acc, 0.f);
        temp[half * 128 + e] = act * row[e];
    } else if (t < 192) {
        temp[64 + (t - 128)] = submrow[t - 128];
    }
    __syncthreads();

    if (t < 128) {
        float acc = b1[t];
        for (int k = 0; k < 192; ++k) acc += temp[k] * W1[k * 128 + t];
        h1[t] = fmaxf(acc, 0.f);
    }
    __syncthreads();
    if (t < 64) {
        float acc = b2[t];
        for (int k = 0; k < 128; ++k) acc += h1[k] * W2[k * 64 + t];
        h2v[t] = fmaxf(acc, 0.f);
    }
    __syncthreads();
    if (t < 32) {
        float acc = b3[t];
        for (int k = 0; k < 64; ++k) acc += h2v[k] * W3[k * 32 + t];
        h3v[t] = fmaxf(acc, 0.f);
    }
    __syncthreads();
    if (t == 0) {
        float acc = b4[0];
        for (int k = 0; k < 32; ++k) acc += h3v[k] * W4[k];
        out[b] = sigmoidf_(acc);
    }
}

extern "C" void kernel_launch(void* const* d_in, const int* in_sizes, int n_in,
                              void* d_out, int out_size, void* d_ws, size_t ws_size,
                              hipStream_t stream)
{
    const int*   node_slice = (const int*)d_in[0];
    const int*   type_slice = (const int*)d_in[1];
    const float* distance   = (const float*)d_in[2];
    const int*   rel_matrix = (const int*)d_in[3];
    const int*   input_len  = (const int*)d_in[4];
    // d_in[5] = isBatch (ignored)
    const float* emb_table  = (const float*)d_in[6];
    const float* type_table = (const float*)d_in[7];
    const float* rel_table  = (const float*)d_in[8];
    const float* W_in = (const float*)d_in[9];  const float* b_in = (const float*)d_in[10];
    const float* Wr   = (const float*)d_in[11]; const float* br   = (const float*)d_in[12];
    const float* Wz   = (const float*)d_in[13]; const float* bz   = (const float*)d_in[14];
    const float* Wt   = (const float*)d_in[15]; const float* bt   = (const float*)d_in[16];
    const float* W_co = (const float*)d_in[17]; const float* b_co = (const float*)d_in[18];
    const float* W1   = (const float*)d_in[19]; const float* b1   = (const float*)d_in[20];
    const float* W2   = (const float*)d_in[21]; const float* b2   = (const float*)d_in[22];
    const float* W3   = (const float*)d_in[23]; const float* b3   = (const float*)d_in[24];
    const float* W4   = (const float*)d_in[25]; const float* b4   = (const float*)d_in[26];

    float* NT  = (float*)d_ws;                  // 128*128*192 f32 = 12.58 MB
    float* Hws = NT + B_ * N_ * 192;            // 128*128*64  f32 =  4.19 MB

    ggnn_pre<<<dim3(512), dim3(256), 0, stream>>>(
        node_slice, type_slice, emb_table, type_table,
        W_in, Wr, br, Wz, bz, Wt, bt, NT, Hws);

    ggnn_main<<<dim3(B_), dim3(256), 0, stream>>>(
        rel_matrix, input_len, distance, rel_table,
        W_in, b_in, Wr, Wz, Wt, W_co, b_co,
        W1, b1, W2, b2, W3, b3, W4, b4,
        NT, Hws, (float*)d_out);
}

// Round 5
// 489.877 us; speedup vs baseline: 3.0097x; 1.0631x over previous
//
#include <hip/hip_runtime.h>
#include <hip/hip_bf16.h>

// GGNN fused scan v4. B=128, N=128, E=64, T=32, R=32.
// ggnn_pre: 1024 blocks, 16 rows each; row addresses are wave-uniform ->
//   scalar s_load path; weight columns in regs. Writes NTbf (bf16) + Hws (f32).
// ggnn_main: 1 block/batch, 256 thr, 4 barriers/step, fully LDS-resident:
//   relL u8 (len-masked), relWb bf16, disc in regs, H_sw f32 XOR-swizzled.
//   Gate/H matvecs via v_readlane (no LDS pipe, no broadcast b128).
//   NT read from global bf16 with 1-step register prefetch (crosses 3+
//   barriers before use -> vmcnt drain is free).
//   w0=r, w1=z, w2=t+upd(+user/item/sub), w3=H-row. Steps i>=len are no-ops.

#define B_ 128
#define N_ 128
#define SW(ee) (((ee) & 7) << 2)   // XOR swizzle: phys_j = j ^ SW(e)

typedef unsigned short u16;
typedef unsigned int u32;

__device__ __forceinline__ float b2f(u16 u) {
    union { u32 i; float f; } c; c.i = ((u32)u) << 16; return c.f;
}
__device__ __forceinline__ u16 f2b(float f) {
    union { float f; u32 i; } c; c.f = f;
    u32 u = c.i;
    return (u16)((u + 0x7fffu + ((u >> 16) & 1u)) >> 16);
}
__device__ __forceinline__ float sigmoidf_(float x) { return 1.0f / (1.0f + __expf(-x)); }
__device__ __forceinline__ float tanhf_(float x) { return 1.0f - 2.0f / (__expf(2.0f * x) + 1.0f); }
__device__ __forceinline__ float rlane(float v, int k) {
    return __int_as_float(__builtin_amdgcn_readlane(__float_as_int(v), k));
}

// ---------------- precompute kernel ----------------
__global__ __launch_bounds__(256, 2) void ggnn_pre(
    const int* __restrict__ node_slice, const int* __restrict__ type_slice,
    const float* __restrict__ emb_table, const float* __restrict__ type_table,
    const float* __restrict__ W_in,
    const float* __restrict__ Wr, const float* __restrict__ br,
    const float* __restrict__ Wz, const float* __restrict__ bz,
    const float* __restrict__ Wt, const float* __restrict__ bt,
    u16* __restrict__ NTbf, float* __restrict__ Hws)
{
    const int b  = blockIdx.x >> 3;
    const int i0 = (blockIdx.x & 7) * 16;
    const int t = threadIdx.x;
    const int w = t >> 6;
    const int e = t & 63;

    float wc[96];
    float bias = 0.f;
    if (w < 3) {
        const float* W  = (w == 0) ? Wr : (w == 1) ? Wz : Wt;
        const float* bb = (w == 0) ? br : (w == 1) ? bz : bt;
        bias = bb[e];
        #pragma unroll
        for (int k = 0; k < 96; ++k) wc[k] = W[k * 64 + e];
    } else {
        #pragma unroll
        for (int k = 0; k < 64; ++k) wc[k] = W_in[k * 64 + e];
        #pragma unroll
        for (int k = 64; k < 96; ++k) wc[k] = 0.f;
    }

    for (int rr = 0; rr < 16; ++rr) {
        const int row = i0 + rr;
        const int node = node_slice[b * N_ + row];   // uniform -> s_load path
        const float* ep = emb_table + node * 64;
        if (w < 3) {
            const int typ = type_slice[b * N_ + row];
            const float* tp = type_table + typ * 32;
            float a0 = bias, a1 = 0.f, a2 = 0.f, a3 = 0.f;
            #pragma unroll
            for (int k = 0; k < 32; k += 4) {
                a0 += tp[k]   * wc[k];
                a1 += tp[k+1] * wc[k+1];
                a2 += tp[k+2] * wc[k+2];
                a3 += tp[k+3] * wc[k+3];
            }
            #pragma unroll
            for (int k = 0; k < 64; k += 4) {
                a0 += ep[k]   * wc[32+k];
                a1 += ep[k+1] * wc[32+k+1];
                a2 += ep[k+2] * wc[32+k+2];
                a3 += ep[k+3] * wc[32+k+3];
            }
            NTbf[(b * N_ + row) * 192 + w * 64 + e] = f2b((a0 + a1) + (a2 + a3));
        } else {
            float a0 = 0.f, a1 = 0.f, a2 = 0.f, a3 = 0.f;
            #pragma unroll
            for (int k = 0; k < 64; k += 4) {
                a0 += ep[k]   * wc[k];
                a1 += ep[k+1] * wc[k+1];
                a2 += ep[k+2] * wc[k+2];
                a3 += ep[k+3] * wc[k+3];
            }
            Hws[(b * N_ + row) * 64 + e] = (a0 + a1) + (a2 + a3);
        }
    }
}

// ---------------- main scan kernel ----------------
__global__ __launch_bounds__(256, 1) void ggnn_main(
    const int* __restrict__ rel_matrix,
    const int* __restrict__ input_length, const float* __restrict__ distance,
    const float* __restrict__ rel_table,
    const float* __restrict__ W_in, const float* __restrict__ b_in,
    const float* __restrict__ Wr, const float* __restrict__ Wz, const float* __restrict__ Wt,
    const float* __restrict__ W_co, const float* __restrict__ b_co,
    const float* __restrict__ W1, const float* __restrict__ b1,
    const float* __restrict__ W2, const float* __restrict__ b2,
    const float* __restrict__ W3, const float* __restrict__ b3,
    const float* __restrict__ W4, const float* __restrict__ b4,
    const u16* __restrict__ NTbf, const float* __restrict__ Hws,
    float* __restrict__ out)
{
    __shared__ __align__(16) float H_sw[64 * 128];        // 32 KB, XOR-swizzled
    __shared__ __align__(16) u16   relWb16[51 * 64];      // 6.4 KB, [r][e] bf16
    __shared__ __align__(16) unsigned char relL[128 * 128]; // 16 KB, len-masked
    __shared__ __align__(16) float disc[N_];
    __shared__ __align__(16) float pmax[256];
    __shared__ __align__(16) float r_row[64], z_row[64], updrow[64];
    __shared__ __align__(16) float userrow[64], itemrow[64], submrow[64];
    __shared__ __align__(16) float temp[192];
    __shared__ float h1[128];
    __shared__ float h2v[64];
    __shared__ float h3v[32];

    const int b = blockIdx.x;
    const int t = threadIdx.x;
    const int w = t >> 6;
    const int e = t & 63;
    const int len = input_length[b];
    const float NEGINF = -__builtin_inff();

    // ---- staging ----
    if (t < N_) disc[t] = -0.1f * distance[b * N_ + t];

    {   // rel_matrix -> u8, len-masked
        const int4* src = (const int4*)(rel_matrix + b * N_ * N_);
        u32* dst = (u32*)relL;
        for (int c = t; c < 4096; c += 256) {
            int4 v = src[c];
            int j = (c * 4) & 127;
            u32 p = (u32)((j + 0 < len && v.x) ? v.x : 0)
                  | ((u32)((j + 1 < len && v.y) ? v.y : 0) << 8)
                  | ((u32)((j + 2 < len && v.z) ? v.z : 0) << 16)
                  | ((u32)((j + 3 < len && v.w) ? v.w : 0) << 24);
            dst[c] = p;
        }
    }
    for (int idx = t; idx < N_ * 64; idx += 256) {        // H_sw <- Hws
        int j = idx >> 6, ee = idx & 63;
        H_sw[(ee << 7) + (j ^ SW(ee))] = Hws[b * N_ * 64 + idx];
    }
    for (int idx = t; idx < 51 * 64; idx += 256) {        // relWb = b_in + rel@W_in_bot
        int r = idx >> 6, ee = idx & 63;
        float acc = b_in[ee];
        #pragma unroll
        for (int k = 0; k < 32; ++k)
            acc += rel_table[r * 32 + k] * W_in[(64 + k) * 64 + ee];
        relWb16[idx] = f2b(acc);
    }

    // per-wave weight column: w0=Wr_bot, w1=Wz_bot, w2=Wt_bot, w3=W_in_top
    float wcol[64];
    {
        const float* wsrc = (w == 0) ? (Wr + 96 * 64) : (w == 1) ? (Wz + 96 * 64)
                          : (w == 2) ? (Wt + 96 * 64) : W_in;
        #pragma unroll
        for (int k = 0; k < 64; ++k) wcol[k] = wsrc[k * 64 + e];
    }

    // NT prefetch (step 0)
    const u16* NTb = NTbf + b * N_ * 192;
    u16 ntc = 0;
    if (w < 3) ntc = NTb[w * 64 + e];
    float user_r = 0.f, item_r = 0.f, subm_r = NEGINF;
    __syncthreads();                                      // A0

    // disc -> regs (after barrier)
    float dreg[32];
    #pragma unroll
    for (int jj = 0; jj < 32; ++jj) dreg[jj] = disc[w * 32 + jj];

    const int sw = SW(e);
    const float* hrow = H_sw + (e << 7);

    // ---- scan ----
    for (int i = 0; i < len; ++i) {
        // max phase: all 4 waves, 32 j each, LDS-resident
        const u32* rrow = (const u32*)(relL + i * 128 + w * 32);
        float m = NEGINF;
        #pragma unroll
        for (int g = 0; g < 8; ++g) {
            u32 d = rrow[g];
            const int j0 = w * 32 + 4 * g;
            float4 hv = *(const float4*)(hrow + (j0 ^ sw));
            int r0 = d & 255, r1 = (d >> 8) & 255, r2 = (d >> 16) & 255, r3 = d >> 24;
            float s0 = fmaxf(hv.x + b2f(relWb16[(r0 << 6) + e]), 0.f) * dreg[4*g+0];
            float s1 = fmaxf(hv.y + b2f(relWb16[(r1 << 6) + e]), 0.f) * dreg[4*g+1];
            float s2 = fmaxf(hv.z + b2f(relWb16[(r2 << 6) + e]), 0.f) * dreg[4*g+2];
            float s3 = fmaxf(hv.w + b2f(relWb16[(r3 << 6) + e]), 0.f) * dreg[4*g+3];
            m = r0 ? fmaxf(m, s0) : m;
            m = r1 ? fmaxf(m, s1) : m;
            m = r2 ? fmaxf(m, s2) : m;
            m = r3 ? fmaxf(m, s3) : m;
        }
        pmax[t] = m;
        __syncthreads();                                  // B

        float mm = fmaxf(fmaxf(pmax[e], pmax[64 + e]),
                         fmaxf(pmax[128 + e], pmax[192 + e]));
        float dis0 = (mm == NEGINF) ? 0.f : mm;

        // NT prefetch for step i+1 (consumed after 3+ barriers -> drain free)
        u16 ntp = 0;
        if (w < 3) ntp = NTb[((i + 1) & 127) * 192 + w * 64 + e];

        if (w == 0) {                                     // r-gate (readlane matvec)
            float a0 = b2f(ntc), a1 = 0.f, a2 = 0.f, a3 = 0.f;
            #pragma unroll
            for (int k = 0; k < 64; k += 4) {
                a0 += rlane(dis0, k)     * wcol[k];
                a1 += rlane(dis0, k + 1) * wcol[k + 1];
                a2 += rlane(dis0, k + 2) * wcol[k + 2];
                a3 += rlane(dis0, k + 3) * wcol[k + 3];
            }
            r_row[e] = sigmoidf_((a0 + a1) + (a2 + a3));
        } else if (w == 1) {                              // z-gate
            float a0 = b2f(ntc), a1 = 0.f, a2 = 0.f, a3 = 0.f;
            #pragma unroll
            for (int k = 0; k < 64; k += 4) {
                a0 += rlane(dis0, k)     * wcol[k];
                a1 += rlane(dis0, k + 1) * wcol[k + 1];
                a2 += rlane(dis0, k + 2) * wcol[k + 2];
                a3 += rlane(dis0, k + 3) * wcol[k + 3];
            }
            z_row[e] = sigmoidf_((a0 + a1) + (a2 + a3));
        }
        __syncthreads();                                  // C

        if (w == 2) {                                     // t-gate + update
            float rdp = r_row[e] * dis0;
            float a0 = b2f(ntc), a1 = 0.f, a2 = 0.f, a3 = 0.f;
            #pragma unroll
            for (int k = 0; k < 64; k += 4) {
                a0 += rlane(rdp, k)     * wcol[k];
                a1 += rlane(rdp, k + 1) * wcol[k + 1];
                a2 += rlane(rdp, k + 2) * wcol[k + 2];
                a3 += rlane(rdp, k + 3) * wcol[k + 3];
            }
            float hh = tanhf_((a0 + a1) + (a2 + a3));
            float z = z_row[e];
            float upd = (1.f - z) * dis0 + z * hh;
            updrow[e] = upd;
            if (i == 0) user_r = upd;
            subm_r = fmaxf(subm_r, upd);
            item_r = upd;
        }
        __syncthreads();                                  // D

        if (w == 3) {                                     // H-row update
            float u = updrow[e];
            float a0 = 0.f, a1 = 0.f, a2 = 0.f, a3 = 0.f;
            #pragma unroll
            for (int k = 0; k < 64; k += 4) {
                a0 += rlane(u, k)     * wcol[k];
                a1 += rlane(u, k + 1) * wcol[k + 1];
                a2 += rlane(u, k + 2) * wcol[k + 2];
                a3 += rlane(u, k + 3) * wcol[k + 3];
            }
            H_sw[(e << 7) + (i ^ sw)] = (a0 + a1) + (a2 + a3);
        }
        ntc = ntp;
        __syncthreads();                                  // A (loop top)
    }

    if (w == 2) { userrow[e] = user_r; itemrow[e] = item_r; submrow[e] = subm_r; }
    __syncthreads();

    // ---- epilogue ----
    if (t < 128) {
        const int half = t >> 6;                // 0: ua*user, 1: ia*item
        const float* row = (half == 0) ? userrow : itemrow;
        float acc = b_co[e];
        #pragma unroll
        for (int k = 0; k < 64; ++k) acc += row[k] * W_co[k * 64 + e];
        #pragma unroll
        for (int k = 0; k < 64; ++k) acc += submrow[k] * W_co[(64 + k) * 64 + e];
        float act = fmaxf(acc, 0.f);
        temp[half * 128 + e] = act * row[e];
    } else if (t < 192) {
        temp[64 + (t - 128)] = submrow[t - 128];
    }
    __syncthreads();

    if (t < 128) {
        float acc = b1[t];
        for (int k = 0; k < 192; ++k) acc += temp[k] * W1[k * 128 + t];
        h1[t] = fmaxf(acc, 0.f);
    }
    __syncthreads();
    if (t < 64) {
        float acc = b2[t];
        for (int k = 0; k < 128; ++k) acc += h1[k] * W2[k * 64 + t];
        h2v[t] = fmaxf(acc, 0.f);
    }
    __syncthreads();
    if (t < 32) {
        float acc = b3[t];
        for (int k = 0; k < 64; ++k) acc += h2v[k] * W3[k * 32 + t];
        h3v[t] = fmaxf(acc, 0.f);
    }
    __syncthreads();
    if (t == 0) {
        float acc = b4[0];
        for (int k = 0; k < 32; ++k) acc += h3v[k] * W4[k];
        out[b] = sigmoidf_(acc);
    }
}

extern "C" void kernel_launch(void* const* d_in, const int* in_sizes, int n_in,
                              void* d_out, int out_size, void* d_ws, size_t ws_size,
                              hipStream_t stream)
{
    const int*   node_slice = (const int*)d_in[0];
    const int*   type_slice = (const int*)d_in[1];
    const float* distance   = (const float*)d_in[2];
    const int*   rel_matrix = (const int*)d_in[3];
    const int*   input_len  = (const int*)d_in[4];
    // d_in[5] = isBatch (ignored)
    const float* emb_table  = (const float*)d_in[6];
    const float* type_table = (const float*)d_in[7];
    const float* rel_table  = (const float*)d_in[8];
    const float* W_in = (const float*)d_in[9];  const float* b_in = (const float*)d_in[10];
    const float* Wr   = (const float*)d_in[11]; const float* br   = (const float*)d_in[12];
    const float* Wz   = (const float*)d_in[13]; const float* bz   = (const float*)d_in[14];
    const float* Wt   = (const float*)d_in[15]; const float* bt   = (const float*)d_in[16];
    const float* W_co = (const float*)d_in[17]; const float* b_co = (const float*)d_in[18];
    const float* W1   = (const float*)d_in[19]; const float* b1   = (const float*)d_in[20];
    const float* W2   = (const float*)d_in[21]; const float* b2   = (const float*)d_in[22];
    const float* W3   = (const float*)d_in[23]; const float* b3   = (const float*)d_in[24];
    const float* W4   = (const float*)d_in[25]; const float* b4   = (const float*)d_in[26];

    u16*   NTbf = (u16*)d_ws;                            // 128*128*192 bf16 = 6.29 MB
    float* Hws  = (float*)((char*)d_ws + (size_t)B_ * N_ * 192 * 2); // 4.19 MB

    ggnn_pre<<<dim3(1024), dim3(256), 0, stream>>>(
        node_slice, type_slice, emb_table, type_table,
        W_in, Wr, br, Wz, bz, Wt, bt, NTbf, Hws);

    ggnn_main<<<dim3(B_), dim3(256), 0, stream>>>(
        rel_matrix, input_len, distance, rel_table,
        W_in, b_in, Wr, Wz, Wt, W_co, b_co,
        W1, b1, W2, b2, W3, b3, W4, b4,
        NTbf, Hws, (float*)d_out);
}